// Round 7
// baseline (202.303 us; speedup 1.0000x reference)
//
#include <hip/hip_runtime.h>
#include <hip/hip_bf16.h>
#include <math.h>

#define BB   16
#define CIN  256
#define HH   64
#define WW   64
#define COUT 256
#define NEXP 4
#define REDC 16
#define HW   (HH*WW)       // 4096

typedef __attribute__((ext_vector_type(8))) short short8;
typedef __attribute__((ext_vector_type(16))) float f32x16;

#define AS1 __attribute__((address_space(1)))
#define AS3 __attribute__((address_space(3)))

__device__ __forceinline__ void gld_lds16(void* lds, const void* gp) {
    __builtin_amdgcn_global_load_lds((const AS1 unsigned int*)gp,
                                     (AS3 unsigned int*)lds, 16, 0, 0);
}

// -------- K0: x (f32, [b][c][s]) -> xT (bf16, [b][s][c]) + pooled partials --------
__global__ __launch_bounds__(256)
void transpose_pool_kernel(const float* __restrict__ x, ushort* __restrict__ xT,
                           float* __restrict__ pp) {
    int blk = blockIdx.x;
    int sq = blk & 3;
    int chunk = (blk >> 2) & 7;
    int b = blk >> 5;
    int c0 = chunk * 32;
    int s0 = sq * 1024;
    int tid = threadIdx.x;
    const float* xb = x + ((size_t)(b * CIN + c0)) * HW;
    ushort* xTb = xT + (size_t)b * HW * CIN;

    float psum[32];
    #pragma unroll
    for (int i = 0; i < 32; ++i) psum[i] = 0.f;

    for (int it = 0; it < 4; ++it) {
        int s = s0 + it * 256 + tid;
        unsigned int pk[16];
        #pragma unroll
        for (int p = 0; p < 16; ++p) {
            float lo = xb[(size_t)(2 * p) * HW + s];
            float hi = xb[(size_t)(2 * p + 1) * HW + s];
            psum[2 * p]     += lo;
            psum[2 * p + 1] += hi;
            asm volatile("v_cvt_pk_bf16_f32 %0, %1, %2" : "=v"(pk[p]) : "v"(lo), "v"(hi));
        }
        uint4* dst = (uint4*)(xTb + (size_t)s * CIN + c0);
        #pragma unroll
        for (int q = 0; q < 4; ++q)
            dst[q] = make_uint4(pk[q * 4], pk[q * 4 + 1], pk[q * 4 + 2], pk[q * 4 + 3]);
    }

    __shared__ float red[4][32];
    int lane = tid & 63, wid = tid >> 6;
    #pragma unroll
    for (int i = 0; i < 32; ++i) {
        float v = psum[i];
        #pragma unroll
        for (int off = 32; off > 0; off >>= 1) v += __shfl_down(v, off, 64);
        if (lane == 0) red[wid][i] = v;
    }
    __syncthreads();
    if (tid < 32)
        pp[(b * 4 + sq) * 256 + c0 + tid] = red[0][tid] + red[1][tid] + red[2][tid] + red[3][tid];
}

// ---------------- K2: routing MLP -> rw[b*1024 + k*256 + c] ----------------
__global__ void route_kernel(const float* __restrict__ pp,
                             const float* __restrict__ w1, const float* __restrict__ b1,
                             const float* __restrict__ w2, const float* __restrict__ b2,
                             float* __restrict__ rw) {
    __shared__ float p_s[BB][CIN];
    __shared__ float r_s[BB][REDC];
    int tid = threadIdx.x;
    for (int i = tid; i < BB * CIN; i += 256) {
        int b = i >> 8, c = i & 255;
        p_s[b][c] = (pp[(b * 4 + 0) * 256 + c] + pp[(b * 4 + 1) * 256 + c] +
                     pp[(b * 4 + 2) * 256 + c] + pp[(b * 4 + 3) * 256 + c]) * (1.0f / HW);
    }
    __syncthreads();
    {
        int b = tid >> 4, j = tid & 15;
        float acc = b1[j];
        for (int c = 0; c < CIN; ++c) acc += p_s[b][c] * w1[j * CIN + c];
        r_s[b][j] = fmaxf(acc, 0.f);
    }
    __syncthreads();
    for (int i = tid; i < BB * NEXP * CIN; i += 256) {
        int b = i >> 10, o2 = i & 1023;
        float acc = b2[o2];
        #pragma unroll
        for (int j = 0; j < REDC; ++j) acc += r_s[b][j] * w2[o2 * REDC + j];
        rw[i] = 1.f / (1.f + expf(-acc));
    }
}

// ------- K3: combined weights, exactly-once coalesced weight reads -------
// Output layout (16-channel chunks, for conv A-frags):
//   idx = ((((b*4+ot)*16 + chunk16)*9 + t9)*2 + g)*512 + o_loc*8 + c8
__global__ __launch_bounds__(256)
void combine2_kernel(const float* __restrict__ rw,
                     const float* __restrict__ weight,
                     ushort* __restrict__ cw) {
    int blk = blockIdx.x;
    int oq    = blk & 3;
    int chunk = (blk >> 2) & 7;   // 32-channel chunk
    int ot    = blk >> 5;
    int tid = threadIdx.x;

    __shared__ float ws_s[4][4][288];   // [k][oo][c*9+t9]
    __shared__ float rw_s[4 * 32 * 16]; // [k][c][b]

    for (int i = tid; i < 2048; i += 256) {
        int b = i >> 7, r = i & 127, k = r >> 5, cc = r & 31;
        rw_s[k * 512 + cc * 16 + b] = rw[b * 1024 + k * 256 + chunk * 32 + cc];
    }
    __syncthreads();

    int b = tid >> 4, low = tid & 15;

    for (int batch = 0; batch < 4; ++batch) {
        #pragma unroll
        for (int r = 0; r < 16; ++r) {
            int k = r >> 2, oo = r & 3;
            const float* wrow = weight +
                ((size_t)(k * COUT + ot * 64 + oq * 16 + batch * 4 + oo) * CIN
                 + chunk * 32) * 9;
            for (int e = tid; e < 288; e += 256) ws_s[k][oo][e] = wrow[e];
        }
        __syncthreads();

        #pragma unroll
        for (int t9 = 0; t9 < 9; ++t9) {
            #pragma unroll
            for (int g = 0; g < 4; ++g) {
                #pragma unroll
                for (int rep = 0; rep < 2; ++rep) {
                    int slot = rep * 16 + low;       // 0..31 = oo*8 + c8
                    int oo = slot >> 3, c8 = slot & 7;
                    int c = g * 8 + c8;
                    float acc = 0.f;
                    #pragma unroll
                    for (int k = 0; k < 4; ++k)
                        acc += rw_s[k * 512 + c * 16 + b] * ws_s[k][oo][c * 9 + t9];
                    __hip_bfloat16 hv = __float2bfloat16(acc);
                    int chunk16 = chunk * 2 + (g >> 1);
                    int gg = g & 1;
                    size_t idx = ((((size_t)(b * 4 + ot) * 16 + chunk16) * 9 + t9) * 2 + gg) * 512
                                 + (oq * 16 + batch * 4 + oo) * 8 + c8;
                    cw[idx] = *(ushort*)&hv;
                }
            }
        }
        __syncthreads();
    }
}

// ---------------- K4: MFMA conv, 32x32x16, dbuf + counted vmcnt ----------------
// 256 blocks x 512 thr (8 waves, 2/SIMD). block = 64 o x 16 rows.
// LDS buf (57344 B x 2): A = [t9][h][64o][8c] at 0 (18432 B);
// X = [half][s][8c] at 18432 (2 x 19456 B). All frag reads are 16B/lane
// contiguous per 32-lane group -> conflict-free. 7 gld_lds16 per wave per
// chunk, counted vmcnt(7) double-buffer pipeline.
__global__ __launch_bounds__(512, 2)
void conv_mfma(const ushort* __restrict__ xT, const ushort* __restrict__ cw,
               float* __restrict__ out, const ushort* __restrict__ zp) {
    __shared__ ushort LDS[2][28672];   // 114688 B

    int blk = blockIdx.x;
    int L = (blk & 7) * 32 + (blk >> 3);   // XCD-chunked swizzle (256 = 8*32)
    int b  = L >> 4;
    int rt = (L >> 2) & 3;
    int ot = L & 3;
    int r0 = rt * 16, o0 = ot * 64;
    int tid = threadIdx.x;
    int lane = tid & 63, wid = tid >> 6;
    int l31 = lane & 31, h = lane >> 5;

    f32x16 acc[2][4];
    #pragma unroll
    for (int mi = 0; mi < 2; ++mi)
        #pragma unroll
        for (int f = 0; f < 4; ++f) acc[mi][f] = (f32x16)0.f;

    const ushort* xTb = xT + (size_t)b * HW * CIN;
    const ushort* Ab  = cw + (size_t)((b * 4 + ot) * 16) * 9216;

    // ---- precompute per-unit staging descriptors (7 units/wave) ----
    const char* srcb[7];
    int dsto[7];   // byte offset within one LDS buffer
    int strd[7];   // byte stride per chunk
    #pragma unroll
    for (int i = 0; i < 7; ++i) {
        int u = wid * 7 + i;
        if (u < 18) {           // A units: contiguous 1 KB each
            srcb[i] = (const char*)(Ab + (size_t)u * 512 + lane * 8);
            dsto[i] = u * 1024;
            strd[i] = 18432;
        } else {                // X units: 64 s-slots of one half
            int ux = u - 18;
            int half = ux & 1, u19 = ux >> 1;
            int s = u19 * 64 + lane;
            int r = (unsigned)s / 66u;
            int cc = s - r * 66;
            int grow = r0 - 1 + r;
            bool valid = (cc >= 1 && cc <= 64 && grow >= 0 && grow < 64 && s < 1188);
            srcb[i] = valid
                ? (const char*)(xTb + (size_t)(grow * 64 + cc - 1) * CIN + half * 8)
                : (const char*)(zp + lane * 8);
            dsto[i] = 18432 + half * 19456 + u19 * 1024;
            strd[i] = 32;       // zp page is 2 KB: +15*32B stays in-page
        }
    }

    char* ldsb = (char*)&LDS[0][0];

    #define STAGE(BUF, CH)                                                    \
    {                                                                         \
        _Pragma("unroll")                                                     \
        for (int i = 0; i < 7; ++i)                                           \
            gld_lds16(ldsb + (BUF) * 57344 + dsto[i],                         \
                      srcb[i] + (size_t)(CH) * strd[i]);                      \
    }

    // prologue: stage chunk 0 into buffer 0
    STAGE(0, 0)

    #pragma unroll 1
    for (int chunk = 0; chunk < 16; ++chunk) {
        int cur = chunk & 1;
        if (chunk < 15) {
            STAGE(cur ^ 1, chunk + 1)
            asm volatile("s_waitcnt vmcnt(7)" ::: "memory");
        } else {
            asm volatile("s_waitcnt vmcnt(0)" ::: "memory");
        }
        __builtin_amdgcn_s_barrier();
        __builtin_amdgcn_sched_barrier(0);

        const ushort* asb = &LDS[cur][0];
        const ushort* xsb = &LDS[cur][9216] + h * 9728;
        #pragma unroll
        for (int t9 = 0; t9 < 9; ++t9) {
            int di = t9 / 3, dj = t9 - di * 3;
            short8 a0 = *(short8*)&asb[((t9 * 2 + h) * 64 + 0  + l31) * 8];
            short8 a1 = *(short8*)&asb[((t9 * 2 + h) * 64 + 32 + l31) * 8];
            short8 b0, b1v, b2v, b3;
            {
                int rr = wid * 2 + di;
                b0  = *(short8*)&xsb[(rr * 66 +  0 + l31 + dj) * 8];
                b1v = *(short8*)&xsb[(rr * 66 + 32 + l31 + dj) * 8];
                b2v = *(short8*)&xsb[((rr + 1) * 66 +  0 + l31 + dj) * 8];
                b3  = *(short8*)&xsb[((rr + 1) * 66 + 32 + l31 + dj) * 8];
            }
            __builtin_amdgcn_s_setprio(1);
            acc[0][0] = __builtin_amdgcn_mfma_f32_32x32x16_bf16(a0, b0,  acc[0][0], 0, 0, 0);
            acc[1][0] = __builtin_amdgcn_mfma_f32_32x32x16_bf16(a1, b0,  acc[1][0], 0, 0, 0);
            acc[0][1] = __builtin_amdgcn_mfma_f32_32x32x16_bf16(a0, b1v, acc[0][1], 0, 0, 0);
            acc[1][1] = __builtin_amdgcn_mfma_f32_32x32x16_bf16(a1, b1v, acc[1][1], 0, 0, 0);
            acc[0][2] = __builtin_amdgcn_mfma_f32_32x32x16_bf16(a0, b2v, acc[0][2], 0, 0, 0);
            acc[1][2] = __builtin_amdgcn_mfma_f32_32x32x16_bf16(a1, b2v, acc[1][2], 0, 0, 0);
            acc[0][3] = __builtin_amdgcn_mfma_f32_32x32x16_bf16(a0, b3,  acc[0][3], 0, 0, 0);
            acc[1][3] = __builtin_amdgcn_mfma_f32_32x32x16_bf16(a1, b3,  acc[1][3], 0, 0, 0);
            __builtin_amdgcn_s_setprio(0);
        }
        __builtin_amdgcn_sched_barrier(0);
        __builtin_amdgcn_s_barrier();   // all waves done reading buf cur
    }

    // ---- epilogue: C 32x32 layout: col(pos)=l31, row(o)=(j&3)+8*(j>>2)+4*h ----
    #pragma unroll
    for (int mi = 0; mi < 2; ++mi) {
        #pragma unroll
        for (int f = 0; f < 4; ++f) {
            int pos = (r0 + wid * 2 + (f >> 1)) * 64 + (f & 1) * 32 + l31;
            #pragma unroll
            for (int j = 0; j < 16; ++j) {
                int orow = (j & 3) + 8 * (j >> 2) + 4 * h;
                out[((size_t)(b * COUT + o0 + mi * 32 + orow)) * HW + pos] = acc[mi][f][j];
            }
        }
    }
    #undef STAGE
}

extern "C" void kernel_launch(void* const* d_in, const int* in_sizes, int n_in,
                              void* d_out, int out_size, void* d_ws, size_t ws_size,
                              hipStream_t stream) {
    const float* x      = (const float*)d_in[0];
    const float* w1     = (const float*)d_in[1];
    const float* b1     = (const float*)d_in[2];
    const float* w2     = (const float*)d_in[3];
    const float* b2     = (const float*)d_in[4];
    const float* weight = (const float*)d_in[5];
    float* out = (float*)d_out;

    float*  ws = (float*)d_ws;
    float*  pp = ws;                              // 16384 f
    float*  rw = ws + 16384;                      // 16384 f
    ushort* cw = (ushort*)(ws + 32768);           // 9437184 ushort (~18.9 MB)
    ushort* xT = (ushort*)(ws + 32768 + 4718592); // 16777216 ushort (~33.6 MB)
    ushort* zp = xT + 16777216;                   // 1024 ushort zero page (2 KB)

    hipMemsetAsync(zp, 0, 2048, stream);
    transpose_pool_kernel<<<512, 256, 0, stream>>>(x, xT, pp);
    route_kernel<<<1, 256, 0, stream>>>(pp, w1, b1, w2, b2, rw);
    combine2_kernel<<<128, 256, 0, stream>>>(rw, weight, cw);
    conv_mfma<<<256, 512, 0, stream>>>(xT, cw, out, zp);
}

// Round 8
// 200.400 us; speedup vs baseline: 1.0095x; 1.0095x over previous
//
#include <hip/hip_runtime.h>
#include <hip/hip_bf16.h>
#include <math.h>

#define BB   16
#define CIN  256
#define HH   64
#define WW   64
#define COUT 256
#define NEXP 4
#define REDC 16
#define HW   (HH*WW)       // 4096

typedef __attribute__((ext_vector_type(8))) short short8;
typedef __attribute__((ext_vector_type(16))) float f32x16;

#define AS1 __attribute__((address_space(1)))
#define AS3 __attribute__((address_space(3)))

__device__ __forceinline__ void gld_lds16(void* lds, const void* gp) {
    __builtin_amdgcn_global_load_lds((const AS1 unsigned int*)gp,
                                     (AS3 unsigned int*)lds, 16, 0, 0);
}

// -------- K0: x (f32, [b][c][s]) -> xT (bf16, [b][s][c]) + pooled partials --------
__global__ __launch_bounds__(256)
void transpose_pool_kernel(const float* __restrict__ x, ushort* __restrict__ xT,
                           float* __restrict__ pp) {
    int blk = blockIdx.x;
    int sq = blk & 3;
    int chunk = (blk >> 2) & 7;
    int b = blk >> 5;
    int c0 = chunk * 32;
    int s0 = sq * 1024;
    int tid = threadIdx.x;
    const float* xb = x + ((size_t)(b * CIN + c0)) * HW;
    ushort* xTb = xT + (size_t)b * HW * CIN;

    float psum[32];
    #pragma unroll
    for (int i = 0; i < 32; ++i) psum[i] = 0.f;

    for (int it = 0; it < 4; ++it) {
        int s = s0 + it * 256 + tid;
        unsigned int pk[16];
        #pragma unroll
        for (int p = 0; p < 16; ++p) {
            float lo = xb[(size_t)(2 * p) * HW + s];
            float hi = xb[(size_t)(2 * p + 1) * HW + s];
            psum[2 * p]     += lo;
            psum[2 * p + 1] += hi;
            asm volatile("v_cvt_pk_bf16_f32 %0, %1, %2" : "=v"(pk[p]) : "v"(lo), "v"(hi));
        }
        uint4* dst = (uint4*)(xTb + (size_t)s * CIN + c0);
        #pragma unroll
        for (int q = 0; q < 4; ++q)
            dst[q] = make_uint4(pk[q * 4], pk[q * 4 + 1], pk[q * 4 + 2], pk[q * 4 + 3]);
    }

    __shared__ float red[4][32];
    int lane = tid & 63, wid = tid >> 6;
    #pragma unroll
    for (int i = 0; i < 32; ++i) {
        float v = psum[i];
        #pragma unroll
        for (int off = 32; off > 0; off >>= 1) v += __shfl_down(v, off, 64);
        if (lane == 0) red[wid][i] = v;
    }
    __syncthreads();
    if (tid < 32)
        pp[(b * 4 + sq) * 256 + c0 + tid] = red[0][tid] + red[1][tid] + red[2][tid] + red[3][tid];
}

// ---------------- K2: routing MLP -> rw[b*1024 + k*256 + c] ----------------
__global__ void route_kernel(const float* __restrict__ pp,
                             const float* __restrict__ w1, const float* __restrict__ b1,
                             const float* __restrict__ w2, const float* __restrict__ b2,
                             float* __restrict__ rw) {
    __shared__ float p_s[BB][CIN];
    __shared__ float r_s[BB][REDC];
    int tid = threadIdx.x;
    for (int i = tid; i < BB * CIN; i += 256) {
        int b = i >> 8, c = i & 255;
        p_s[b][c] = (pp[(b * 4 + 0) * 256 + c] + pp[(b * 4 + 1) * 256 + c] +
                     pp[(b * 4 + 2) * 256 + c] + pp[(b * 4 + 3) * 256 + c]) * (1.0f / HW);
    }
    __syncthreads();
    {
        int b = tid >> 4, j = tid & 15;
        float acc = b1[j];
        for (int c = 0; c < CIN; ++c) acc += p_s[b][c] * w1[j * CIN + c];
        r_s[b][j] = fmaxf(acc, 0.f);
    }
    __syncthreads();
    for (int i = tid; i < BB * NEXP * CIN; i += 256) {
        int b = i >> 10, o2 = i & 1023;
        float acc = b2[o2];
        #pragma unroll
        for (int j = 0; j < REDC; ++j) acc += r_s[b][j] * w2[o2 * REDC + j];
        rw[i] = 1.f / (1.f + expf(-acc));
    }
}

// ------- K3: combined weights, exactly-once coalesced weight reads -------
// Output layout (16-channel chunks, for conv A-frags):
//   idx = ((((b*4+ot)*16 + chunk16)*9 + t9)*2 + g)*512 + o_loc*8 + c8
__global__ __launch_bounds__(256)
void combine2_kernel(const float* __restrict__ rw,
                     const float* __restrict__ weight,
                     ushort* __restrict__ cw) {
    int blk = blockIdx.x;
    int oq    = blk & 3;
    int chunk = (blk >> 2) & 7;   // 32-channel chunk
    int ot    = blk >> 5;
    int tid = threadIdx.x;

    __shared__ float ws_s[4][4][288];   // [k][oo][c*9+t9]
    __shared__ float rw_s[4 * 32 * 16]; // [k][c][b]

    for (int i = tid; i < 2048; i += 256) {
        int b = i >> 7, r = i & 127, k = r >> 5, cc = r & 31;
        rw_s[k * 512 + cc * 16 + b] = rw[b * 1024 + k * 256 + chunk * 32 + cc];
    }
    __syncthreads();

    int b = tid >> 4, low = tid & 15;

    for (int batch = 0; batch < 4; ++batch) {
        #pragma unroll
        for (int r = 0; r < 16; ++r) {
            int k = r >> 2, oo = r & 3;
            const float* wrow = weight +
                ((size_t)(k * COUT + ot * 64 + oq * 16 + batch * 4 + oo) * CIN
                 + chunk * 32) * 9;
            for (int e = tid; e < 288; e += 256) ws_s[k][oo][e] = wrow[e];
        }
        __syncthreads();

        #pragma unroll
        for (int t9 = 0; t9 < 9; ++t9) {
            #pragma unroll
            for (int g = 0; g < 4; ++g) {
                #pragma unroll
                for (int rep = 0; rep < 2; ++rep) {
                    int slot = rep * 16 + low;       // 0..31 = oo*8 + c8
                    int oo = slot >> 3, c8 = slot & 7;
                    int c = g * 8 + c8;
                    float acc = 0.f;
                    #pragma unroll
                    for (int k = 0; k < 4; ++k)
                        acc += rw_s[k * 512 + c * 16 + b] * ws_s[k][oo][c * 9 + t9];
                    __hip_bfloat16 hv = __float2bfloat16(acc);
                    int chunk16 = chunk * 2 + (g >> 1);
                    int gg = g & 1;
                    size_t idx = ((((size_t)(b * 4 + ot) * 16 + chunk16) * 9 + t9) * 2 + gg) * 512
                                 + (oq * 16 + batch * 4 + oo) * 8 + c8;
                    cw[idx] = *(ushort*)&hv;
                }
            }
        }
        __syncthreads();
    }
}

// ---------------- K4: MFMA conv, 32x32x16, dbuf + counted vmcnt ----------------
// 256 blocks x 512 thr (8 waves, 2/SIMD). block = 64 o x 16 rows.
// LDS buf (57344 B x 2): A = [t9][h][64o][8c] at 0; X = [half][s][8c] at 18432.
// Compute phase: 2-slot fragment pipeline — tap t+1's ds_reads issue before
// tap t's MFMAs (no setprio/fences inside; compiler emits counted lgkmcnt).
__global__ __launch_bounds__(512, 2)
void conv_mfma(const ushort* __restrict__ xT, const ushort* __restrict__ cw,
               float* __restrict__ out, const ushort* __restrict__ zp) {
    __shared__ ushort LDS[2][28672];   // 114688 B

    int blk = blockIdx.x;
    int L = (blk & 7) * 32 + (blk >> 3);   // XCD-chunked swizzle (256 = 8*32)
    int b  = L >> 4;
    int rt = (L >> 2) & 3;
    int ot = L & 3;
    int r0 = rt * 16, o0 = ot * 64;
    int tid = threadIdx.x;
    int lane = tid & 63, wid = tid >> 6;
    int l31 = lane & 31, h = lane >> 5;

    f32x16 acc[2][4];
    #pragma unroll
    for (int mi = 0; mi < 2; ++mi)
        #pragma unroll
        for (int f = 0; f < 4; ++f) acc[mi][f] = (f32x16)0.f;

    const ushort* xTb = xT + (size_t)b * HW * CIN;
    const ushort* Ab  = cw + (size_t)((b * 4 + ot) * 16) * 9216;

    // ---- precompute per-unit staging descriptors (7 units/wave) ----
    const char* srcb[7];
    int dsto[7];
    int strd[7];
    #pragma unroll
    for (int i = 0; i < 7; ++i) {
        int u = wid * 7 + i;
        if (u < 18) {           // A units: contiguous 1 KB each
            srcb[i] = (const char*)(Ab + (size_t)u * 512 + lane * 8);
            dsto[i] = u * 1024;
            strd[i] = 18432;
        } else {                // X units: 64 s-slots of one half
            int ux = u - 18;
            int half = ux & 1, u19 = ux >> 1;
            int s = u19 * 64 + lane;
            int r = (unsigned)s / 66u;
            int cc = s - r * 66;
            int grow = r0 - 1 + r;
            bool valid = (cc >= 1 && cc <= 64 && grow >= 0 && grow < 64 && s < 1188);
            srcb[i] = valid
                ? (const char*)(xTb + (size_t)(grow * 64 + cc - 1) * CIN + half * 8)
                : (const char*)(zp + lane * 8);
            dsto[i] = 18432 + half * 19456 + u19 * 1024;
            strd[i] = 32;       // zp page is 2 KB: +15*32B stays in-page
        }
    }

    char* ldsb = (char*)&LDS[0][0];

    #define STAGE(BUF, CH)                                                    \
    {                                                                         \
        _Pragma("unroll")                                                     \
        for (int i = 0; i < 7; ++i)                                           \
            gld_lds16(ldsb + (BUF) * 57344 + dsto[i],                         \
                      srcb[i] + (size_t)(CH) * strd[i]);                      \
    }

    #define LOADT(T, va0, va1, vb0, vb1, vb2, vb3)                            \
    {                                                                         \
        const int di_ = (T) / 3, dj_ = (T) - di_ * 3;                         \
        va0 = *(const short8*)&asb[(((T) * 2 + h) * 64 + 0  + l31) * 8];      \
        va1 = *(const short8*)&asb[(((T) * 2 + h) * 64 + 32 + l31) * 8];      \
        const int rr_ = wid * 2 + di_;                                        \
        vb0 = *(const short8*)&xsb[(rr_ * 66 +  0 + l31 + dj_) * 8];          \
        vb1 = *(const short8*)&xsb[(rr_ * 66 + 32 + l31 + dj_) * 8];          \
        vb2 = *(const short8*)&xsb[((rr_ + 1) * 66 +  0 + l31 + dj_) * 8];    \
        vb3 = *(const short8*)&xsb[((rr_ + 1) * 66 + 32 + l31 + dj_) * 8];    \
    }

    #define DOMM(va0, va1, vb0, vb1, vb2, vb3)                                          \
    {                                                                                   \
        acc[0][0] = __builtin_amdgcn_mfma_f32_32x32x16_bf16(va0, vb0, acc[0][0], 0,0,0);\
        acc[1][0] = __builtin_amdgcn_mfma_f32_32x32x16_bf16(va1, vb0, acc[1][0], 0,0,0);\
        acc[0][1] = __builtin_amdgcn_mfma_f32_32x32x16_bf16(va0, vb1, acc[0][1], 0,0,0);\
        acc[1][1] = __builtin_amdgcn_mfma_f32_32x32x16_bf16(va1, vb1, acc[1][1], 0,0,0);\
        acc[0][2] = __builtin_amdgcn_mfma_f32_32x32x16_bf16(va0, vb2, acc[0][2], 0,0,0);\
        acc[1][2] = __builtin_amdgcn_mfma_f32_32x32x16_bf16(va1, vb2, acc[1][2], 0,0,0);\
        acc[0][3] = __builtin_amdgcn_mfma_f32_32x32x16_bf16(va0, vb3, acc[0][3], 0,0,0);\
        acc[1][3] = __builtin_amdgcn_mfma_f32_32x32x16_bf16(va1, vb3, acc[1][3], 0,0,0);\
    }

    // prologue: stage chunk 0 into buffer 0
    STAGE(0, 0)

    #pragma unroll 1
    for (int chunk = 0; chunk < 16; ++chunk) {
        int cur = chunk & 1;
        if (chunk < 15) {
            STAGE(cur ^ 1, chunk + 1)
            asm volatile("s_waitcnt vmcnt(7)" ::: "memory");
        } else {
            asm volatile("s_waitcnt vmcnt(0)" ::: "memory");
        }
        __builtin_amdgcn_s_barrier();
        __builtin_amdgcn_sched_barrier(0);

        const ushort* asb = &LDS[cur][0];
        const ushort* xsb = &LDS[cur][9216] + h * 9728;

        short8 a0A, a1A, b0A, b1A, b2A, b3A;
        short8 a0B, a1B, b0B, b1B, b2B, b3B;

        LOADT(0, a0A, a1A, b0A, b1A, b2A, b3A)
        LOADT(1, a0B, a1B, b0B, b1B, b2B, b3B)
        DOMM(a0A, a1A, b0A, b1A, b2A, b3A)          // tap 0
        LOADT(2, a0A, a1A, b0A, b1A, b2A, b3A)
        DOMM(a0B, a1B, b0B, b1B, b2B, b3B)          // tap 1
        LOADT(3, a0B, a1B, b0B, b1B, b2B, b3B)
        DOMM(a0A, a1A, b0A, b1A, b2A, b3A)          // tap 2
        LOADT(4, a0A, a1A, b0A, b1A, b2A, b3A)
        DOMM(a0B, a1B, b0B, b1B, b2B, b3B)          // tap 3
        LOADT(5, a0B, a1B, b0B, b1B, b2B, b3B)
        DOMM(a0A, a1A, b0A, b1A, b2A, b3A)          // tap 4
        LOADT(6, a0A, a1A, b0A, b1A, b2A, b3A)
        DOMM(a0B, a1B, b0B, b1B, b2B, b3B)          // tap 5
        LOADT(7, a0B, a1B, b0B, b1B, b2B, b3B)
        DOMM(a0A, a1A, b0A, b1A, b2A, b3A)          // tap 6
        LOADT(8, a0A, a1A, b0A, b1A, b2A, b3A)
        DOMM(a0B, a1B, b0B, b1B, b2B, b3B)          // tap 7
        DOMM(a0A, a1A, b0A, b1A, b2A, b3A)          // tap 8

        __builtin_amdgcn_sched_barrier(0);
        __builtin_amdgcn_s_barrier();   // all waves done reading buf cur
    }

    // ---- epilogue: C 32x32 layout: col(pos)=l31, row(o)=(j&3)+8*(j>>2)+4*h ----
    #pragma unroll
    for (int mi = 0; mi < 2; ++mi) {
        #pragma unroll
        for (int f = 0; f < 4; ++f) {
            int pos = (r0 + wid * 2 + (f >> 1)) * 64 + (f & 1) * 32 + l31;
            #pragma unroll
            for (int j = 0; j < 16; ++j) {
                int orow = (j & 3) + 8 * (j >> 2) + 4 * h;
                out[((size_t)(b * COUT + o0 + mi * 32 + orow)) * HW + pos] = acc[mi][f][j];
            }
        }
    }
    #undef STAGE
    #undef LOADT
    #undef DOMM
}

extern "C" void kernel_launch(void* const* d_in, const int* in_sizes, int n_in,
                              void* d_out, int out_size, void* d_ws, size_t ws_size,
                              hipStream_t stream) {
    const float* x      = (const float*)d_in[0];
    const float* w1     = (const float*)d_in[1];
    const float* b1     = (const float*)d_in[2];
    const float* w2     = (const float*)d_in[3];
    const float* b2     = (const float*)d_in[4];
    const float* weight = (const float*)d_in[5];
    float* out = (float*)d_out;

    float*  ws = (float*)d_ws;
    float*  pp = ws;                              // 16384 f
    float*  rw = ws + 16384;                      // 16384 f
    ushort* cw = (ushort*)(ws + 32768);           // 9437184 ushort (~18.9 MB)
    ushort* xT = (ushort*)(ws + 32768 + 4718592); // 16777216 ushort (~33.6 MB)
    ushort* zp = xT + 16777216;                   // 1024 ushort zero page (2 KB)

    hipMemsetAsync(zp, 0, 2048, stream);
    transpose_pool_kernel<<<512, 256, 0, stream>>>(x, xT, pp);
    route_kernel<<<1, 256, 0, stream>>>(pp, w1, b1, w2, b2, rw);
    combine2_kernel<<<128, 256, 0, stream>>>(rw, weight, cw);
    conv_mfma<<<256, 512, 0, stream>>>(xT, cw, out, zp);
}

// Round 10
// 157.482 us; speedup vs baseline: 1.2846x; 1.2725x over previous
//
#include <hip/hip_runtime.h>
#include <hip/hip_bf16.h>
#include <math.h>

#define BB   16
#define CIN  256
#define HH   64
#define WW   64
#define COUT 256
#define NEXP 4
#define REDC 16
#define HW   (HH*WW)       // 4096

typedef __attribute__((ext_vector_type(8))) short short8;
typedef __attribute__((ext_vector_type(16))) float f32x16;

#define AS1 __attribute__((address_space(1)))
#define AS3 __attribute__((address_space(3)))

__device__ __forceinline__ void gld_lds16(void* lds, const void* gp) {
    __builtin_amdgcn_global_load_lds((const AS1 unsigned int*)gp,
                                     (AS3 unsigned int*)lds, 16, 0, 0);
}

// -------- K0: x (f32, [b][c][s]) -> xT (bf16, [b][s][c]) + pooled partials --------
__global__ __launch_bounds__(256)
void transpose_pool_kernel(const float* __restrict__ x, ushort* __restrict__ xT,
                           float* __restrict__ pp) {
    int blk = blockIdx.x;
    int sq = blk & 3;
    int chunk = (blk >> 2) & 7;
    int b = blk >> 5;
    int c0 = chunk * 32;
    int s0 = sq * 1024;
    int tid = threadIdx.x;
    const float* xb = x + ((size_t)(b * CIN + c0)) * HW;
    ushort* xTb = xT + (size_t)b * HW * CIN;

    float psum[32];
    #pragma unroll
    for (int i = 0; i < 32; ++i) psum[i] = 0.f;

    for (int it = 0; it < 4; ++it) {
        int s = s0 + it * 256 + tid;
        unsigned int pk[16];
        #pragma unroll
        for (int p = 0; p < 16; ++p) {
            float lo = xb[(size_t)(2 * p) * HW + s];
            float hi = xb[(size_t)(2 * p + 1) * HW + s];
            psum[2 * p]     += lo;
            psum[2 * p + 1] += hi;
            asm volatile("v_cvt_pk_bf16_f32 %0, %1, %2" : "=v"(pk[p]) : "v"(lo), "v"(hi));
        }
        uint4* dst = (uint4*)(xTb + (size_t)s * CIN + c0);
        #pragma unroll
        for (int q = 0; q < 4; ++q)
            dst[q] = make_uint4(pk[q * 4], pk[q * 4 + 1], pk[q * 4 + 2], pk[q * 4 + 3]);
    }

    __shared__ float red[4][32];
    int lane = tid & 63, wid = tid >> 6;
    #pragma unroll
    for (int i = 0; i < 32; ++i) {
        float v = psum[i];
        #pragma unroll
        for (int off = 32; off > 0; off >>= 1) v += __shfl_down(v, off, 64);
        if (lane == 0) red[wid][i] = v;
    }
    __syncthreads();
    if (tid < 32)
        pp[(b * 4 + sq) * 256 + c0 + tid] = red[0][tid] + red[1][tid] + red[2][tid] + red[3][tid];
}

// ---------------- K2: routing MLP -> rw[b*1024 + k*256 + c] ----------------
__global__ void route_kernel(const float* __restrict__ pp,
                             const float* __restrict__ w1, const float* __restrict__ b1,
                             const float* __restrict__ w2, const float* __restrict__ b2,
                             float* __restrict__ rw) {
    __shared__ float p_s[BB][CIN];
    __shared__ float r_s[BB][REDC];
    int tid = threadIdx.x;
    for (int i = tid; i < BB * CIN; i += 256) {
        int b = i >> 8, c = i & 255;
        p_s[b][c] = (pp[(b * 4 + 0) * 256 + c] + pp[(b * 4 + 1) * 256 + c] +
                     pp[(b * 4 + 2) * 256 + c] + pp[(b * 4 + 3) * 256 + c]) * (1.0f / HW);
    }
    __syncthreads();
    {
        int b = tid >> 4, j = tid & 15;
        float acc = b1[j];
        for (int c = 0; c < CIN; ++c) acc += p_s[b][c] * w1[j * CIN + c];
        r_s[b][j] = fmaxf(acc, 0.f);
    }
    __syncthreads();
    for (int i = tid; i < BB * NEXP * CIN; i += 256) {
        int b = i >> 10, o2 = i & 1023;
        float acc = b2[o2];
        #pragma unroll
        for (int j = 0; j < REDC; ++j) acc += r_s[b][j] * w2[o2 * REDC + j];
        rw[i] = 1.f / (1.f + expf(-acc));
    }
}

// ------- K3 v3: combined weights, flat-parallel, b-loop inside -------
// cw idx = (b*1152 + u)*512 + t,  u = ((ot*16+chunk16)*9+t9)*2+gg, t = o_loc*8+c8
// grid: 2304 blocks x 256 thr (each block: fixed u, half the t-range).
__global__ __launch_bounds__(256)
void combine3_kernel(const float* __restrict__ rw,
                     const float* __restrict__ weight,
                     ushort* __restrict__ cw) {
    int blk = blockIdx.x;
    int u = blk >> 1;
    int t = (blk & 1) * 256 + threadIdx.x;    // 0..511
    int gg = u & 1;
    int v = u >> 1;
    int t9 = v % 9;
    int cu = v / 9;           // 0..63
    int chunk16 = cu & 15;
    int ot = cu >> 4;
    int o_loc = t >> 3, c8 = t & 7;
    int o = ot * 64 + o_loc;
    int c = chunk16 * 16 + gg * 8 + c8;

    __shared__ float rw_s[16][4][8];
    int tid = threadIdx.x;
    #pragma unroll
    for (int r = 0; r < 2; ++r) {
        int i = r * 256 + tid;
        if (i < 512) {
            int b = i >> 5, k = (i >> 3) & 3, cc = i & 7;
            rw_s[b][k][cc] = rw[b * 1024 + k * 256 + chunk16 * 16 + gg * 8 + cc];
        }
    }
    __syncthreads();

    float wk0 = weight[((size_t)(0 * COUT + o) * CIN + c) * 9 + t9];
    float wk1 = weight[((size_t)(1 * COUT + o) * CIN + c) * 9 + t9];
    float wk2 = weight[((size_t)(2 * COUT + o) * CIN + c) * 9 + t9];
    float wk3 = weight[((size_t)(3 * COUT + o) * CIN + c) * 9 + t9];

    size_t base = (size_t)u * 512 + t;
    #pragma unroll
    for (int b = 0; b < 16; ++b) {
        float acc = rw_s[b][0][c8] * wk0 + rw_s[b][1][c8] * wk1 +
                    rw_s[b][2][c8] * wk2 + rw_s[b][3][c8] * wk3;
        __hip_bfloat16 hv = __float2bfloat16(acc);
        cw[base + (size_t)b * 589824] = *(ushort*)&hv;
    }
}

// ---------------- K4: MFMA conv, 32x32x16, dbuf + counted vmcnt (R8-verified) ----------------
// 256 blocks x 512 thr (8 waves, 2/SIMD). block = 64 o x 16 rows.
// LDS buf (57344 B x 2): A = [t9][gg][64o][8c] at 0; X = [half][s][8c] at 18432.
// Compute phase: 2-slot fragment pipeline — tap t+1's ds_reads issue before
// tap t's MFMAs (no setprio/fences inside; compiler emits counted lgkmcnt).
__global__ __launch_bounds__(512, 2)
void conv_mfma(const ushort* __restrict__ xT, const ushort* __restrict__ cw,
               float* __restrict__ out, const ushort* __restrict__ zp) {
    __shared__ ushort LDS[2][28672];   // 114688 B

    int blk = blockIdx.x;
    int L = (blk & 7) * 32 + (blk >> 3);   // XCD-chunked swizzle (256 = 8*32)
    int b  = L >> 4;
    int rt = (L >> 2) & 3;
    int ot = L & 3;
    int r0 = rt * 16, o0 = ot * 64;
    int tid = threadIdx.x;
    int lane = tid & 63, wid = tid >> 6;
    int l31 = lane & 31, h = lane >> 5;

    f32x16 acc[2][4];
    #pragma unroll
    for (int mi = 0; mi < 2; ++mi)
        #pragma unroll
        for (int f = 0; f < 4; ++f) acc[mi][f] = (f32x16)0.f;

    const ushort* xTb = xT + (size_t)b * HW * CIN;
    const ushort* Ab  = cw + (size_t)((b * 4 + ot) * 16) * 9216;

    // ---- precompute per-unit staging descriptors (7 units/wave) ----
    const char* srcb[7];
    int dsto[7];
    int strd[7];
    #pragma unroll
    for (int i = 0; i < 7; ++i) {
        int u = wid * 7 + i;
        if (u < 18) {           // A units: contiguous 1 KB each
            srcb[i] = (const char*)(Ab + (size_t)u * 512 + lane * 8);
            dsto[i] = u * 1024;
            strd[i] = 18432;
        } else {                // X units: 64 s-slots of one half
            int ux = u - 18;
            int half = ux & 1, u19 = ux >> 1;
            int s = u19 * 64 + lane;
            int r = (unsigned)s / 66u;
            int cc = s - r * 66;
            int grow = r0 - 1 + r;
            bool valid = (cc >= 1 && cc <= 64 && grow >= 0 && grow < 64 && s < 1188);
            srcb[i] = valid
                ? (const char*)(xTb + (size_t)(grow * 64 + cc - 1) * CIN + half * 8)
                : (const char*)(zp + lane * 8);
            dsto[i] = 18432 + half * 19456 + u19 * 1024;
            strd[i] = 32;       // zp page is 2 KB: +15*32B stays in-page
        }
    }

    char* ldsb = (char*)&LDS[0][0];

    #define STAGE(BUF, CH)                                                    \
    {                                                                         \
        _Pragma("unroll")                                                     \
        for (int i = 0; i < 7; ++i)                                           \
            gld_lds16(ldsb + (BUF) * 57344 + dsto[i],                         \
                      srcb[i] + (size_t)(CH) * strd[i]);                      \
    }

    #define LOADT(T, va0, va1, vb0, vb1, vb2, vb3)                            \
    {                                                                         \
        const int di_ = (T) / 3, dj_ = (T) - di_ * 3;                         \
        va0 = *(const short8*)&asb[(((T) * 2 + h) * 64 + 0  + l31) * 8];      \
        va1 = *(const short8*)&asb[(((T) * 2 + h) * 64 + 32 + l31) * 8];      \
        const int rr_ = wid * 2 + di_;                                        \
        vb0 = *(const short8*)&xsb[(rr_ * 66 +  0 + l31 + dj_) * 8];          \
        vb1 = *(const short8*)&xsb[(rr_ * 66 + 32 + l31 + dj_) * 8];          \
        vb2 = *(const short8*)&xsb[((rr_ + 1) * 66 +  0 + l31 + dj_) * 8];    \
        vb3 = *(const short8*)&xsb[((rr_ + 1) * 66 + 32 + l31 + dj_) * 8];    \
    }

    #define DOMM(va0, va1, vb0, vb1, vb2, vb3)                                          \
    {                                                                                   \
        acc[0][0] = __builtin_amdgcn_mfma_f32_32x32x16_bf16(va0, vb0, acc[0][0], 0,0,0);\
        acc[1][0] = __builtin_amdgcn_mfma_f32_32x32x16_bf16(va1, vb0, acc[1][0], 0,0,0);\
        acc[0][1] = __builtin_amdgcn_mfma_f32_32x32x16_bf16(va0, vb1, acc[0][1], 0,0,0);\
        acc[1][1] = __builtin_amdgcn_mfma_f32_32x32x16_bf16(va1, vb1, acc[1][1], 0,0,0);\
        acc[0][2] = __builtin_amdgcn_mfma_f32_32x32x16_bf16(va0, vb2, acc[0][2], 0,0,0);\
        acc[1][2] = __builtin_amdgcn_mfma_f32_32x32x16_bf16(va1, vb2, acc[1][2], 0,0,0);\
        acc[0][3] = __builtin_amdgcn_mfma_f32_32x32x16_bf16(va0, vb3, acc[0][3], 0,0,0);\
        acc[1][3] = __builtin_amdgcn_mfma_f32_32x32x16_bf16(va1, vb3, acc[1][3], 0,0,0);\
    }

    // prologue: stage chunk 0 into buffer 0
    STAGE(0, 0)

    #pragma unroll 1
    for (int chunk = 0; chunk < 16; ++chunk) {
        int cur = chunk & 1;
        if (chunk < 15) {
            STAGE(cur ^ 1, chunk + 1)
            asm volatile("s_waitcnt vmcnt(7)" ::: "memory");
        } else {
            asm volatile("s_waitcnt vmcnt(0)" ::: "memory");
        }
        __builtin_amdgcn_s_barrier();
        __builtin_amdgcn_sched_barrier(0);

        const ushort* asb = &LDS[cur][0];
        const ushort* xsb = &LDS[cur][9216] + h * 9728;

        short8 a0A, a1A, b0A, b1A, b2A, b3A;
        short8 a0B, a1B, b0B, b1B, b2B, b3B;

        LOADT(0, a0A, a1A, b0A, b1A, b2A, b3A)
        LOADT(1, a0B, a1B, b0B, b1B, b2B, b3B)
        DOMM(a0A, a1A, b0A, b1A, b2A, b3A)          // tap 0
        LOADT(2, a0A, a1A, b0A, b1A, b2A, b3A)
        DOMM(a0B, a1B, b0B, b1B, b2B, b3B)          // tap 1
        LOADT(3, a0B, a1B, b0B, b1B, b2B, b3B)
        DOMM(a0A, a1A, b0A, b1A, b2A, b3A)          // tap 2
        LOADT(4, a0A, a1A, b0A, b1A, b2A, b3A)
        DOMM(a0B, a1B, b0B, b1B, b2B, b3B)          // tap 3
        LOADT(5, a0B, a1B, b0B, b1B, b2B, b3B)
        DOMM(a0A, a1A, b0A, b1A, b2A, b3A)          // tap 4
        LOADT(6, a0A, a1A, b0A, b1A, b2A, b3A)
        DOMM(a0B, a1B, b0B, b1B, b2B, b3B)          // tap 5
        LOADT(7, a0B, a1B, b0B, b1B, b2B, b3B)
        DOMM(a0A, a1A, b0A, b1A, b2A, b3A)          // tap 6
        LOADT(8, a0A, a1A, b0A, b1A, b2A, b3A)
        DOMM(a0B, a1B, b0B, b1B, b2B, b3B)          // tap 7
        DOMM(a0A, a1A, b0A, b1A, b2A, b3A)          // tap 8

        __builtin_amdgcn_sched_barrier(0);
        __builtin_amdgcn_s_barrier();   // all waves done reading buf cur
    }

    // ---- epilogue: C 32x32 layout: col(pos)=l31, row(o)=(j&3)+8*(j>>2)+4*h ----
    #pragma unroll
    for (int mi = 0; mi < 2; ++mi) {
        #pragma unroll
        for (int f = 0; f < 4; ++f) {
            int pos = (r0 + wid * 2 + (f >> 1)) * 64 + (f & 1) * 32 + l31;
            #pragma unroll
            for (int j = 0; j < 16; ++j) {
                int orow = (j & 3) + 8 * (j >> 2) + 4 * h;
                out[((size_t)(b * COUT + o0 + mi * 32 + orow)) * HW + pos] = acc[mi][f][j];
            }
        }
    }
    #undef STAGE
    #undef LOADT
    #undef DOMM
}

extern "C" void kernel_launch(void* const* d_in, const int* in_sizes, int n_in,
                              void* d_out, int out_size, void* d_ws, size_t ws_size,
                              hipStream_t stream) {
    const float* x      = (const float*)d_in[0];
    const float* w1     = (const float*)d_in[1];
    const float* b1     = (const float*)d_in[2];
    const float* w2     = (const float*)d_in[3];
    const float* b2     = (const float*)d_in[4];
    const float* weight = (const float*)d_in[5];
    float* out = (float*)d_out;

    float*  ws = (float*)d_ws;
    float*  pp = ws;                              // 16384 f
    float*  rw = ws + 16384;                      // 16384 f
    ushort* cw = (ushort*)(ws + 32768);           // 9437184 ushort (~18.9 MB)
    ushort* xT = (ushort*)(ws + 32768 + 4718592); // 16777216 ushort (~33.6 MB)
    ushort* zp = xT + 16777216;                   // 1024 ushort zero page (2 KB)

    hipMemsetAsync(zp, 0, 2048, stream);
    transpose_pool_kernel<<<512, 256, 0, stream>>>(x, xT, pp);
    route_kernel<<<1, 256, 0, stream>>>(pp, w1, b1, w2, b2, rw);
    combine3_kernel<<<2304, 256, 0, stream>>>(rw, weight, cw);
    conv_mfma<<<256, 512, 0, stream>>>(xT, cw, out, zp);
}

// Round 11
// 143.240 us; speedup vs baseline: 1.4123x; 1.0994x over previous
//
#include <hip/hip_runtime.h>
#include <hip/hip_bf16.h>
#include <math.h>

#define BB   16
#define CIN  256
#define HH   64
#define WW   64
#define COUT 256
#define NEXP 4
#define REDC 16
#define HW   (HH*WW)       // 4096

typedef __attribute__((ext_vector_type(8))) short short8;
typedef __attribute__((ext_vector_type(16))) float f32x16;

#define AS1 __attribute__((address_space(1)))
#define AS3 __attribute__((address_space(3)))

__device__ __forceinline__ void gld_lds16(void* lds, const void* gp) {
    __builtin_amdgcn_global_load_lds((const AS1 unsigned int*)gp,
                                     (AS3 unsigned int*)lds, 16, 0, 0);
}

// -------- K0: x (f32, [b][c][s]) -> xT (bf16, [b][hgrp][s][8c]) + pooled partials ----
// hgrp = c >> 3 (32 groups of 8 channels). Adjacent threads write adjacent 16 B.
__global__ __launch_bounds__(256)
void transpose_pool_kernel(const float* __restrict__ x, ushort* __restrict__ xT,
                           float* __restrict__ pp) {
    int blk = blockIdx.x;
    int sq = blk & 3;
    int chunk = (blk >> 2) & 7;
    int b = blk >> 5;
    int c0 = chunk * 32;
    int s0 = sq * 1024;
    int tid = threadIdx.x;
    const float* xb = x + ((size_t)(b * CIN + c0)) * HW;

    float psum[32];
    #pragma unroll
    for (int i = 0; i < 32; ++i) psum[i] = 0.f;

    for (int it = 0; it < 4; ++it) {
        int s = s0 + it * 256 + tid;
        unsigned int pk[16];
        #pragma unroll
        for (int p = 0; p < 16; ++p) {
            float lo = xb[(size_t)(2 * p) * HW + s];
            float hi = xb[(size_t)(2 * p + 1) * HW + s];
            psum[2 * p]     += lo;
            psum[2 * p + 1] += hi;
            asm volatile("v_cvt_pk_bf16_f32 %0, %1, %2" : "=v"(pk[p]) : "v"(lo), "v"(hi));
        }
        // xT: [b][hgrp (32)][s (4096)][8 c]; hgrp = chunk*4 + q
        #pragma unroll
        for (int q = 0; q < 4; ++q) {
            ushort* dst = xT + ((size_t)(b * 32 + chunk * 4 + q) * HW + s) * 8;
            *(uint4*)dst = make_uint4(pk[q * 4], pk[q * 4 + 1], pk[q * 4 + 2], pk[q * 4 + 3]);
        }
    }

    __shared__ float red[4][32];
    int lane = tid & 63, wid = tid >> 6;
    #pragma unroll
    for (int i = 0; i < 32; ++i) {
        float v = psum[i];
        #pragma unroll
        for (int off = 32; off > 0; off >>= 1) v += __shfl_down(v, off, 64);
        if (lane == 0) red[wid][i] = v;
    }
    __syncthreads();
    if (tid < 32)
        pp[(b * 4 + sq) * 256 + c0 + tid] = red[0][tid] + red[1][tid] + red[2][tid] + red[3][tid];
}

// ---------------- K2: routing MLP -> rw[b*1024 + k*256 + c] ----------------
__global__ void route_kernel(const float* __restrict__ pp,
                             const float* __restrict__ w1, const float* __restrict__ b1,
                             const float* __restrict__ w2, const float* __restrict__ b2,
                             float* __restrict__ rw) {
    __shared__ float p_s[BB][CIN];
    __shared__ float r_s[BB][REDC];
    int tid = threadIdx.x;
    for (int i = tid; i < BB * CIN; i += 256) {
        int b = i >> 8, c = i & 255;
        p_s[b][c] = (pp[(b * 4 + 0) * 256 + c] + pp[(b * 4 + 1) * 256 + c] +
                     pp[(b * 4 + 2) * 256 + c] + pp[(b * 4 + 3) * 256 + c]) * (1.0f / HW);
    }
    __syncthreads();
    {
        int b = tid >> 4, j = tid & 15;
        float acc = b1[j];
        for (int c = 0; c < CIN; ++c) acc += p_s[b][c] * w1[j * CIN + c];
        r_s[b][j] = fmaxf(acc, 0.f);
    }
    __syncthreads();
    for (int i = tid; i < BB * NEXP * CIN; i += 256) {
        int b = i >> 10, o2 = i & 1023;
        float acc = b2[o2];
        #pragma unroll
        for (int j = 0; j < REDC; ++j) acc += r_s[b][j] * w2[o2 * REDC + j];
        rw[i] = 1.f / (1.f + expf(-acc));
    }
}

// ------- K3 v3: combined weights, flat-parallel, b-loop inside -------
// cw idx = (b*1152 + u)*512 + t,  u = ((ot*16+chunk16)*9+t9)*2+gg, t = o_loc*8+c8
__global__ __launch_bounds__(256)
void combine3_kernel(const float* __restrict__ rw,
                     const float* __restrict__ weight,
                     ushort* __restrict__ cw) {
    int blk = blockIdx.x;
    int u = blk >> 1;
    int t = (blk & 1) * 256 + threadIdx.x;    // 0..511
    int gg = u & 1;
    int v = u >> 1;
    int t9 = v % 9;
    int cu = v / 9;           // 0..63
    int chunk16 = cu & 15;
    int ot = cu >> 4;
    int o_loc = t >> 3, c8 = t & 7;
    int o = ot * 64 + o_loc;
    int c = chunk16 * 16 + gg * 8 + c8;

    __shared__ float rw_s[16][4][8];
    int tid = threadIdx.x;
    #pragma unroll
    for (int r = 0; r < 2; ++r) {
        int i = r * 256 + tid;
        if (i < 512) {
            int b = i >> 5, k = (i >> 3) & 3, cc = i & 7;
            rw_s[b][k][cc] = rw[b * 1024 + k * 256 + chunk16 * 16 + gg * 8 + cc];
        }
    }
    __syncthreads();

    float wk0 = weight[((size_t)(0 * COUT + o) * CIN + c) * 9 + t9];
    float wk1 = weight[((size_t)(1 * COUT + o) * CIN + c) * 9 + t9];
    float wk2 = weight[((size_t)(2 * COUT + o) * CIN + c) * 9 + t9];
    float wk3 = weight[((size_t)(3 * COUT + o) * CIN + c) * 9 + t9];

    size_t base = (size_t)u * 512 + t;
    #pragma unroll
    for (int b = 0; b < 16; ++b) {
        float acc = rw_s[b][0][c8] * wk0 + rw_s[b][1][c8] * wk1 +
                    rw_s[b][2][c8] * wk2 + rw_s[b][3][c8] * wk3;
        __hip_bfloat16 hv = __float2bfloat16(acc);
        cw[base + (size_t)b * 589824] = *(ushort*)&hv;
    }
}

// ---------------- K4: MFMA conv, 32x32x16, dbuf + counted vmcnt ----------------
// 256 blocks x 512 thr (8 waves). block = 64 o x 16 rows. Per-buffer (57472 B):
//   A  [t9][gg][64o][8c]              at 0      (18432 B)
//   X  [half][slot = r*66+cc][8c]     at 18432  (38016 B; 2 x 1188 slots x 16 B)
//   dummy scratch                     at 56448  (1024 B)   <- R9 bug fix: full 1 KB
// ALL staging units are contiguous 1 KB global reads (xT [hgrp][s][8c] layout).
// 54 real + 2 dummy units -> uniform 7 gld_lds16/wave/chunk, vmcnt(7) pipeline.
// Compute/epilogue byte-identical to the R8-verified kernel.
__global__ __launch_bounds__(512, 2)
void conv_mfma(const ushort* __restrict__ xT, const ushort* __restrict__ cw,
               float* __restrict__ out, const ushort* __restrict__ zp) {
    __shared__ char LDS[2][57472];   // 114944 B

    int blk = blockIdx.x;
    int L = (blk & 7) * 32 + (blk >> 3);   // XCD-chunked swizzle (256 = 8*32)
    int b  = L >> 4;
    int rt = (L >> 2) & 3;
    int ot = L & 3;
    int r0 = rt * 16, o0 = ot * 64;
    int tid = threadIdx.x;
    int lane = tid & 63, wid = tid >> 6;
    int l31 = lane & 31, h = lane >> 5;

    f32x16 acc[2][4];
    #pragma unroll
    for (int mi = 0; mi < 2; ++mi)
        #pragma unroll
        for (int f = 0; f < 4; ++f) acc[mi][f] = (f32x16)0.f;

    const char* xTb = (const char*)(xT + (size_t)b * 32 * HW * 8);  // [32 hgrp][4096 s][8c]
    const ushort* Ab = cw + (size_t)((b * 4 + ot) * 16) * 9216;

    // ---- per-unit staging descriptors (uniform 7 units/wave) ----
    const char* srcb[7];
    int dsto[7];   // byte offset within one LDS buffer
    int strd[7];   // byte stride per chunk16
    #pragma unroll
    for (int i = 0; i < 7; ++i) {
        int u = wid * 7 + i;
        if (u < 18) {            // A units: contiguous 1 KB each
            srcb[i] = (const char*)(Ab + (size_t)u * 512) + lane * 16;
            dsto[i] = u * 1024;
            strd[i] = 18432;
        } else if (u < 54) {     // X units: one (row, half), contiguous 1 KB
            int ux = u - 18;
            int r = ux >> 1, half = ux & 1;
            int grow = r0 - 1 + r;
            bool valid = (grow >= 0 && grow < 64);
            srcb[i] = valid
                ? xTb + (size_t)(half * HW + grow * 64) * 16 + lane * 16
                : (const char*)zp + lane * 16;
            dsto[i] = 18432 + (half * 1188 + r * 66 + 1) * 16;
            strd[i] = valid ? 131072 : 0;   // hgrp += 2 per chunk16
        } else {                 // dummy: keep per-wave count uniform
            srcb[i] = (const char*)zp + lane * 16;
            dsto[i] = 56448;                 // 1 KB scratch, in-bounds
            strd[i] = 0;
        }
    }

    char* ldsb = &LDS[0][0];

    // zero-init all of LDS once (X halo slots must stay 0 across all chunks)
    for (int i = tid; i < 28736; i += 512) ((unsigned int*)ldsb)[i] = 0;
    __syncthreads();

    #define STAGE(BUF, CH)                                                    \
    {                                                                         \
        _Pragma("unroll")                                                     \
        for (int i = 0; i < 7; ++i)                                           \
            gld_lds16(ldsb + (BUF) * 57472 + dsto[i],                         \
                      srcb[i] + (size_t)(CH) * strd[i]);                      \
    }

    #define LOADT(T, va0, va1, vb0, vb1, vb2, vb3)                            \
    {                                                                         \
        const int di_ = (T) / 3, dj_ = (T) - di_ * 3;                         \
        va0 = *(const short8*)&asb[(((T) * 2 + h) * 64 + 0  + l31) * 8];      \
        va1 = *(const short8*)&asb[(((T) * 2 + h) * 64 + 32 + l31) * 8];      \
        const int rr_ = wid * 2 + di_;                                        \
        vb0 = *(const short8*)&xsb[(rr_ * 66 +  0 + l31 + dj_) * 8];          \
        vb1 = *(const short8*)&xsb[(rr_ * 66 + 32 + l31 + dj_) * 8];          \
        vb2 = *(const short8*)&xsb[((rr_ + 1) * 66 +  0 + l31 + dj_) * 8];    \
        vb3 = *(const short8*)&xsb[((rr_ + 1) * 66 + 32 + l31 + dj_) * 8];    \
    }

    #define DOMM(va0, va1, vb0, vb1, vb2, vb3)                                          \
    {                                                                                   \
        acc[0][0] = __builtin_amdgcn_mfma_f32_32x32x16_bf16(va0, vb0, acc[0][0], 0,0,0);\
        acc[1][0] = __builtin_amdgcn_mfma_f32_32x32x16_bf16(va1, vb0, acc[1][0], 0,0,0);\
        acc[0][1] = __builtin_amdgcn_mfma_f32_32x32x16_bf16(va0, vb1, acc[0][1], 0,0,0);\
        acc[1][1] = __builtin_amdgcn_mfma_f32_32x32x16_bf16(va1, vb1, acc[1][1], 0,0,0);\
        acc[0][2] = __builtin_amdgcn_mfma_f32_32x32x16_bf16(va0, vb2, acc[0][2], 0,0,0);\
        acc[1][2] = __builtin_amdgcn_mfma_f32_32x32x16_bf16(va1, vb2, acc[1][2], 0,0,0);\
        acc[0][3] = __builtin_amdgcn_mfma_f32_32x32x16_bf16(va0, vb3, acc[0][3], 0,0,0);\
        acc[1][3] = __builtin_amdgcn_mfma_f32_32x32x16_bf16(va1, vb3, acc[1][3], 0,0,0);\
    }

    // prologue: stage chunk 0 into buffer 0
    STAGE(0, 0)

    #pragma unroll 1
    for (int chunk = 0; chunk < 16; ++chunk) {
        int cur = chunk & 1;
        if (chunk < 15) {
            STAGE(cur ^ 1, chunk + 1)
            asm volatile("s_waitcnt vmcnt(7)" ::: "memory");
        } else {
            asm volatile("s_waitcnt vmcnt(0)" ::: "memory");
        }
        __builtin_amdgcn_s_barrier();
        __builtin_amdgcn_sched_barrier(0);

        const ushort* asb = (const ushort*)(ldsb + cur * 57472);
        const ushort* xsb = (const ushort*)(ldsb + cur * 57472 + 18432) + h * 9504;

        short8 a0A, a1A, b0A, b1A, b2A, b3A;
        short8 a0B, a1B, b0B, b1B, b2B, b3B;

        LOADT(0, a0A, a1A, b0A, b1A, b2A, b3A)
        LOADT(1, a0B, a1B, b0B, b1B, b2B, b3B)
        DOMM(a0A, a1A, b0A, b1A, b2A, b3A)          // tap 0
        LOADT(2, a0A, a1A, b0A, b1A, b2A, b3A)
        DOMM(a0B, a1B, b0B, b1B, b2B, b3B)          // tap 1
        LOADT(3, a0B, a1B, b0B, b1B, b2B, b3B)
        DOMM(a0A, a1A, b0A, b1A, b2A, b3A)          // tap 2
        LOADT(4, a0A, a1A, b0A, b1A, b2A, b3A)
        DOMM(a0B, a1B, b0B, b1B, b2B, b3B)          // tap 3
        LOADT(5, a0B, a1B, b0B, b1B, b2B, b3B)
        DOMM(a0A, a1A, b0A, b1A, b2A, b3A)          // tap 4
        LOADT(6, a0A, a1A, b0A, b1A, b2A, b3A)
        DOMM(a0B, a1B, b0B, b1B, b2B, b3B)          // tap 5
        LOADT(7, a0B, a1B, b0B, b1B, b2B, b3B)
        DOMM(a0A, a1A, b0A, b1A, b2A, b3A)          // tap 6
        LOADT(8, a0A, a1A, b0A, b1A, b2A, b3A)
        DOMM(a0B, a1B, b0B, b1B, b2B, b3B)          // tap 7
        DOMM(a0A, a1A, b0A, b1A, b2A, b3A)          // tap 8

        __builtin_amdgcn_sched_barrier(0);
        __builtin_amdgcn_s_barrier();   // all waves done reading buf cur
    }

    // ---- epilogue: C 32x32 layout: col(pos)=l31, row(o)=(j&3)+8*(j>>2)+4*h ----
    #pragma unroll
    for (int mi = 0; mi < 2; ++mi) {
        #pragma unroll
        for (int f = 0; f < 4; ++f) {
            int pos = (r0 + wid * 2 + (f >> 1)) * 64 + (f & 1) * 32 + l31;
            #pragma unroll
            for (int j = 0; j < 16; ++j) {
                int orow = (j & 3) + 8 * (j >> 2) + 4 * h;
                out[((size_t)(b * COUT + o0 + mi * 32 + orow)) * HW + pos] = acc[mi][f][j];
            }
        }
    }
    #undef STAGE
    #undef LOADT
    #undef DOMM
}

extern "C" void kernel_launch(void* const* d_in, const int* in_sizes, int n_in,
                              void* d_out, int out_size, void* d_ws, size_t ws_size,
                              hipStream_t stream) {
    const float* x      = (const float*)d_in[0];
    const float* w1     = (const float*)d_in[1];
    const float* b1     = (const float*)d_in[2];
    const float* w2     = (const float*)d_in[3];
    const float* b2     = (const float*)d_in[4];
    const float* weight = (const float*)d_in[5];
    float* out = (float*)d_out;

    float*  ws = (float*)d_ws;
    float*  pp = ws;                              // 16384 f
    float*  rw = ws + 16384;                      // 16384 f
    ushort* cw = (ushort*)(ws + 32768);           // 9437184 ushort (~18.9 MB)
    ushort* xT = (ushort*)(ws + 32768 + 4718592); // 16777216 ushort (~33.6 MB)
    ushort* zp = xT + 16777216;                   // 1024 ushort zero page (2 KB)

    hipMemsetAsync(zp, 0, 2048, stream);
    transpose_pool_kernel<<<512, 256, 0, stream>>>(x, xT, pp);
    route_kernel<<<1, 256, 0, stream>>>(pp, w1, b1, w2, b2, rw);
    combine3_kernel<<<2304, 256, 0, stream>>>(rw, weight, cw);
    conv_mfma<<<256, 512, 0, stream>>>(xT, cw, out, zp);
}